// Round 9
// baseline (11708.419 us; speedup 1.0000x reference)
//
#include <hip/hip_runtime.h>
#include <hip/hip_bf16.h>

// LatticeLSTM on MI355X — Round 9: latency engineering on the R8 protocol.
//  - 512-thread WGs, 16 WGs/seq (grid (8,16)): 2 waves/SIMD latency hiding,
//    same per-thread work (32 cols/WG, 16-lane groups), half the producers
//    per broadcast (less publisher spread), 1 pend word polled per thread.
//  - Staggered 2-in-flight polls: two outstanding loads per word, checked
//    alternately (compiler emits vmcnt(1)) -> detect granularity ~RT/2.
//  - x/sense staging for t+1 issued at TOP of phase A (drains before S1,
//    not inside S2's critical wait); h publish issued before out stores.
//  - Protocol unchanged from R8: u64 {val,gen} agent-scope relaxed atomics;
//    packed bf16 h broadcast (2 cols/word); fp32 pend.
// pmask is data-independent: m0=(t>=1), m1=(t>=3); c_plain only at t=0.
// Progress needs all 128 WGs co-resident (1 WG/CU; LDS ~11KB, VGPR<256).

#define Bq 8
#define Tq 1024
#define DCq 128
#define Hq 512
#define NWG 16            // WGs per sequence
#define NTHR 512
#define NGRP 32           // 16-lane column groups per WG

typedef unsigned long long u64;

// ws byte offsets
#define HPUB_OFF  0u         // u64 h_pub[8][2][256]     = 32768 (gap to 65536)
#define PENDP_OFF 65536u     // u64 pend[8][4][2][512]   = 262144
#define WIHT_OFF  327680u    // bf16 [1536][128]
#define WHHT_OFF  720896u    // bf16 [1536][512]
#define AWIHT_OFF 2293760u   // bf16 [512][128]
#define AWHHT_OFF 2424832u   // bf16 [512][512]
#define WWIHT_OFF 2949120u   // bf16 [1536][128]
#define WWHHT_OFF 3342336u   // bf16 [1536][512]  (end 4915200)

__device__ __forceinline__ float bflo(unsigned u){ return __uint_as_float(u << 16); }
__device__ __forceinline__ float bfhi(unsigned u){ return __uint_as_float(u & 0xffff0000u); }
__device__ __forceinline__ float sigm(float x){ return 1.0f / (1.0f + __expf(-x)); }

// fp32 -> bf16 bits (RNE)
__device__ __forceinline__ unsigned f2bf(float f){
  unsigned u = __float_as_uint(f);
  u += 0x7fffu + ((u >> 16) & 1u);
  return u >> 16;
}

__device__ __forceinline__ void fma4(float& acc, uint2 w, float4 v){
  acc = fmaf(bflo(w.x), v.x, acc);
  acc = fmaf(bfhi(w.x), v.y, acc);
  acc = fmaf(bflo(w.y), v.z, acc);
  acc = fmaf(bfhi(w.y), v.w, acc);
}

__device__ __forceinline__ float red16(float x){
  x += __shfl_xor(x, 8, 16);
  x += __shfl_xor(x, 4, 16);
  x += __shfl_xor(x, 2, 16);
  x += __shfl_xor(x, 1, 16);
  return x;
}

__device__ __forceinline__ u64 pack64(float v, unsigned gen){
  return ((u64)gen << 32) | (u64)__float_as_uint(v);
}
__device__ __forceinline__ void st64(u64* p, u64 w){
  __hip_atomic_store(p, w, __ATOMIC_RELAXED, __HIP_MEMORY_SCOPE_AGENT);
}
__device__ __forceinline__ void pub64(u64* p, float v, unsigned gen){
  st64(p, pack64(v, gen));
}
__device__ __forceinline__ u64 ld64(const u64* p){
  return __hip_atomic_load(p, __ATOMIC_RELAXED, __HIP_MEMORY_SCOPE_AGENT);
}
__device__ __forceinline__ unsigned genof(u64 v){ return (unsigned)(v >> 32); }
__device__ __forceinline__ float valof(u64 v){ return __uint_as_float((unsigned)v); }

// src [K][N] fp32 -> dst [N][K] bf16 (transpose + convert). K is pow2.
__global__ void transpose_bf16(const float* __restrict__ src, __hip_bfloat16* __restrict__ dst,
                               int kshift, int total, int N){
  const int K = 1 << kshift;
  for (int idx = blockIdx.x * blockDim.x + threadIdx.x; idx < total;
       idx += gridDim.x * blockDim.x){
    int n = idx >> kshift;
    int k = idx & (K - 1);
    dst[idx] = __float2bfloat16(src[(size_t)k * N + n]);
  }
}

__global__ void __launch_bounds__(NTHR, 2)
lattice_main(const float* __restrict__ char_emb,
             const int*   __restrict__ word_ids,
             const float* __restrict__ sense_table,
             const float* __restrict__ bias_b,
             const float* __restrict__ bias_ab,
             const float* __restrict__ bias_wb,
             unsigned char* __restrict__ ws,
             float* __restrict__ out)
{
  const int seq  = blockIdx.x;
  const int wg   = blockIdx.y;
  const int tid  = threadIdx.x;
  const int grp  = tid >> 4;                    // 0..31
  const int lane = tid & 15;
  const int J    = wg * NGRP + grp;             // owned H column (0..511)

  u64* hpub = (u64*)(ws + HPUB_OFF)  + (size_t)seq * 2 * 256;     // [parity][word]
  u64* pnd  = (u64*)(ws + PENDP_OFF) + (size_t)seq * 4 * 2 * Hq;  // [slot][k][col]

  const uint2* w_ihT  = (const uint2*)(ws + WIHT_OFF);
  const uint2* w_hhT  = (const uint2*)(ws + WHHT_OFF);
  const uint2* aw_ihT = (const uint2*)(ws + AWIHT_OFF);
  const uint2* aw_hhT = (const uint2*)(ws + AWHHT_OFF);
  const uint2* ww_ihT = (const uint2*)(ws + WWIHT_OFF);
  const uint2* ww_hhT = (const uint2*)(ws + WWHHT_OFF);

  // ---- hoist ALL weights into registers (addresses are t-invariant) ----
  uint2 Rwhh_i[8], Rwhh_o[8], Rwhh_g[8], Rawhh[8];
  uint2 Rwwh_f[8], Rwwh_i[8], Rwwh_g[8];
  uint2 Rwih_i[2], Rwih_o[2], Rwih_g[2], Rawih[2];
  uint2 Rwwi_f[2], Rwwi_i[2], Rwwi_g[2];
  {
    const uint2* whh_i = w_hhT  + (size_t)(0*Hq + J) * 128;
    const uint2* whh_o = w_hhT  + (size_t)(1*Hq + J) * 128;
    const uint2* whh_g = w_hhT  + (size_t)(2*Hq + J) * 128;
    const uint2* awhh  = aw_hhT + (size_t)J * 128;
    const uint2* wwh_f = ww_hhT + (size_t)(0*Hq + J) * 128;
    const uint2* wwh_i = ww_hhT + (size_t)(1*Hq + J) * 128;
    const uint2* wwh_g = ww_hhT + (size_t)(2*Hq + J) * 128;
#pragma unroll
    for (int it = 0; it < 8; ++it){
      const int q = it * 16 + lane;
      Rwhh_i[it] = whh_i[q];  Rwhh_o[it] = whh_o[q];  Rwhh_g[it] = whh_g[q];
      Rawhh[it]  = awhh[q];
      Rwwh_f[it] = wwh_f[q];  Rwwh_i[it] = wwh_i[q];  Rwwh_g[it] = wwh_g[q];
    }
    const uint2* wih_i = w_ihT  + (size_t)(0*Hq + J) * 32;
    const uint2* wih_o = w_ihT  + (size_t)(1*Hq + J) * 32;
    const uint2* wih_g = w_ihT  + (size_t)(2*Hq + J) * 32;
    const uint2* awih  = aw_ihT + (size_t)J * 32;
    const uint2* wwi_f = ww_ihT + (size_t)(0*Hq + J) * 32;
    const uint2* wwi_i = ww_ihT + (size_t)(1*Hq + J) * 32;
    const uint2* wwi_g = ww_ihT + (size_t)(2*Hq + J) * 32;
#pragma unroll
    for (int it = 0; it < 2; ++it){
      const int q = it * 16 + lane;
      Rwih_i[it] = wih_i[q];  Rwih_o[it] = wih_o[q];  Rwih_g[it] = wih_g[q];
      Rawih[it]  = awih[q];
      Rwwi_f[it] = wwi_f[q];  Rwwi_i[it] = wwi_i[q];  Rwwi_g[it] = wwi_g[q];
    }
  }

  const float b_i  = bias_b[J], b_o = bias_b[Hq + J], b_g = bias_b[2*Hq + J];
  const float ab_J = bias_ab[J];
  const float wb_f = bias_wb[J], wb_i = bias_wb[Hq + J], wb_g = bias_wb[2*Hq + J];

  float* out_h = out + (size_t)seq * Tq * Hq;            // hs block
  float* out_c = out + ((size_t)Bq + seq) * Tq * Hq;     // cs block

  __shared__ __align__(16) float shH[2][Hq];      // h by parity: shH[t&1] = h(t)
  __shared__ __align__(16) float sh_p0[Hq];
  __shared__ __align__(16) float sh_p1[Hq];
  __shared__ __align__(16) float shx[2][DCq];     // x(t) in shx[t&1]
  __shared__ __align__(16) float shxw0[2][DCq];   // xw(t) in shxw*[t&1]
  __shared__ __align__(16) float shxw1[2][DCq];

  // ---- pre-loop staging: zeros + x(0), xw(0) ----
  shH[0][tid & 511] = 0.f;
  shH[1][tid & 511] = 0.f;
  sh_p0[tid & 511] = 0.f;
  sh_p1[tid & 511] = 0.f;
  if (tid < DCq){
    shx[0][tid] = char_emb[((size_t)seq * Tq + 0) * DCq + tid];
  } else if (tid < 2 * DCq){
    const int k = tid - DCq;
    const int w0 = word_ids[(size_t)seq * Tq * 2 + 0];
    shxw0[0][k] = sense_table[(size_t)w0 * DCq + k];
  } else if (tid < 3 * DCq){
    const int k = tid - 2 * DCq;
    const int w1 = word_ids[(size_t)seq * Tq * 2 + 1];
    shxw1[0][k] = sense_table[(size_t)w1 * DCq + k];
  }
  __syncthreads();

  for (int t = 0; t < Tq; ++t){
    const int par = t & 1;
    const float* hprev = shH[par ^ 1];     // h(t-1)

    // ---- TOP: stage x/xw(t+1) (HBM loads drain before S1, off critical S2) ----
    {
      const int tn = (t + 1 < Tq) ? t + 1 : t;
      if (tid < DCq){
        shx[par ^ 1][tid] = char_emb[((size_t)seq * Tq + tn) * DCq + tid];
      } else if (tid < 2 * DCq){
        const int k = tid - DCq;
        const int w0 = word_ids[((size_t)seq * Tq + tn) * 2 + 0];
        shxw0[par ^ 1][k] = sense_table[(size_t)w0 * DCq + k];
      } else if (tid < 3 * DCq){
        const int k = tid - 2 * DCq;
        const int w1 = word_ids[((size_t)seq * Tq + tn) * 2 + 1];
        shxw1[par ^ 1][k] = sense_table[(size_t)w1 * DCq + k];
      }
    }

    // ---- pend PREFETCH: first in-flight sample (1 word each per thread) ----
    const u64* p0 = pnd + ((size_t)(t & 3) * 2 + 0) * Hq + tid;
    const u64* p1 = pnd + ((size_t)(t & 3) * 2 + 1) * Hq + tid;
    u64 a0 = 0, a1 = 0;
    if (t >= 1){ a0 = ld64(p0); }
    if (t >= 3){ a1 = ld64(p1); }

    // ---- A1: i/o/g/xa matvecs (pend NOT needed) ----
    float a_i = 0.f, a_o = 0.f, a_g = 0.f, a_xa = 0.f;
#pragma unroll
    for (int it = 0; it < 8; ++it){
      const int k0 = it * 64 + lane * 4;
      float4 hv = *(const float4*)(hprev + k0);
      fma4(a_i, Rwhh_i[it], hv);
      fma4(a_o, Rwhh_o[it], hv);
      fma4(a_g, Rwhh_g[it], hv);
    }
#pragma unroll
    for (int it = 0; it < 2; ++it){
      const int k0 = it * 64 + lane * 4;
      float4 xv = *(const float4*)(shx[par] + k0);
      fma4(a_i,  Rwih_i[it], xv);
      fma4(a_o,  Rwih_o[it], xv);
      fma4(a_g,  Rwih_g[it], xv);
      fma4(a_xa, Rawih[it],  xv);
    }
    // h-independent reductions BEFORE S1 (execute under any poll wait)
    a_i  = red16(a_i);  a_o  = red16(a_o);  a_g  = red16(a_g);  a_xa = red16(a_xa);

    // ---- A2: staggered 2-in-flight pend poll ----
    if (t >= 3){
      const unsigned tg0 = (unsigned)t, tg1 = (unsigned)(t - 2);
      u64 b0 = ld64(p0), b1 = ld64(p1);       // second sample in flight
      for (;;){
        if (genof(a0) >= tg0 && genof(a1) >= tg1) break;
        a0 = ld64(p0); a1 = ld64(p1);
        if (genof(b0) >= tg0 && genof(b1) >= tg1){ a0 = b0; a1 = b1; break; }
        b0 = ld64(p0); b1 = ld64(p1);
      }
      sh_p0[tid] = valof(a0);
      sh_p1[tid] = valof(a1);
    } else if (t >= 1){
      const unsigned tg0 = (unsigned)t;
      u64 b0 = ld64(p0);
      for (;;){
        if (genof(a0) >= tg0) break;
        a0 = ld64(p0);
        if (genof(b0) >= tg0){ a0 = b0; break; }
        b0 = ld64(p0);
      }
      sh_p0[tid] = valof(a0);
      // sh_p1 stays zero (m1=0 for t<3)
    }
    __syncthreads();   // S1

    // ---- A3: alpha matvecs + gates -> publish h (packed 2 cols/word) ----
    float a_p0 = 0.f, a_p1 = 0.f;
#pragma unroll
    for (int it = 0; it < 8; ++it){
      const int k0 = it * 64 + lane * 4;
      float4 p0v = *(const float4*)(sh_p0 + k0);
      float4 p1v = *(const float4*)(sh_p1 + k0);
      fma4(a_p0, Rawhh[it], p0v);
      fma4(a_p1, Rawhh[it], p1v);
    }
    a_p0 = red16(a_p0); a_p1 = red16(a_p1);

    const float gi = sigm(a_i + b_i);
    const float go = sigm(a_o + b_o);
    const float gg = tanhf(a_g + b_g);
    float c1;
    if (t == 0){
      c1 = gi * gg;                       // c_plain with c=0
    } else {
      const float base = a_xa + ab_J;
      const float ea0 = __expf(sigm(base + a_p0));   // m0=1 for t>=1
      const float ei  = __expf(gi);
      float num = ei * gg + ea0 * sh_p0[J];
      float den = ei + ea0;
      if (t >= 3){                                    // m1=1 for t>=3
        const float ea1 = __expf(sigm(base + a_p1));
        num += ea1 * sh_p1[J];
        den += ea1;
      }
      c1 = num / den;
    }
    const float h1 = go * tanhf(c1);
    // pair h1 of adjacent groups: lane l <-> l^16 (groups 2k <-> 2k+1)
    const float h1o = __shfl_xor(h1, 16);   // all lanes hold h1 post-red16
    if (lane == 0){
      if ((grp & 1) == 0){
        const u64 w = ((u64)(unsigned)(t + 1) << 32)
                    | ((u64)f2bf(h1o) << 16) | (u64)f2bf(h1);
        st64(hpub + (size_t)par * 256 + (J >> 1), w);   // publish FIRST
      }
      out_h[(size_t)t * Hq + J] = h1;
      out_c[(size_t)t * Hq + J] = c1;
    }

    // ---- B-pre (h NOT needed): x-word matvecs ----
    float x_f0 = 0.f, x_i0 = 0.f, x_g0 = 0.f, x_f1 = 0.f, x_i1 = 0.f, x_g1 = 0.f;
#pragma unroll
    for (int it = 0; it < 2; ++it){
      const int k0 = it * 64 + lane * 4;
      float4 x0 = *(const float4*)(shxw0[par] + k0);
      float4 x1 = *(const float4*)(shxw1[par] + k0);
      fma4(x_f0, Rwwi_f[it], x0);  fma4(x_f1, Rwwi_f[it], x1);
      fma4(x_i0, Rwwi_i[it], x0);  fma4(x_i1, Rwwi_i[it], x1);
      fma4(x_g0, Rwwi_g[it], x0);  fma4(x_g1, Rwwi_g[it], x1);
    }
    x_f0 = red16(x_f0); x_i0 = red16(x_i0); x_g0 = red16(x_g0);
    x_f1 = red16(x_f1); x_i1 = red16(x_i1); x_g1 = red16(x_g1);

    // ---- B2: staggered poll packed h(t) — threads 0..255, 1 word each ----
    if (tid < 256){
      const u64* hp = hpub + (size_t)par * 256 + tid;
      const unsigned tg = (unsigned)(t + 1);
      u64 a = ld64(hp), b = ld64(hp);
      for (;;){
        if (genof(a) >= tg) break;
        a = ld64(hp);
        if (genof(b) >= tg){ a = b; break; }
        b = ld64(hp);
      }
      shH[par][2 * tid]     = bflo((unsigned)a & 0xffffu);
      shH[par][2 * tid + 1] = bflo(((unsigned)a >> 16) & 0xffffu);
    }
    __syncthreads();   // S2

    // ---- B3: word h-matvecs + gates -> publish pend ----
    float r_f = 0.f, r_i = 0.f, r_g = 0.f;
#pragma unroll
    for (int it = 0; it < 8; ++it){
      const int k0 = it * 64 + lane * 4;
      float4 hv = *(const float4*)(shH[par] + k0);
      fma4(r_f, Rwwh_f[it], hv);
      fma4(r_i, Rwwh_i[it], hv);
      fma4(r_g, Rwwh_g[it], hv);
    }
    r_f = red16(r_f); r_i = red16(r_i); r_g = red16(r_g);

    if (lane == 0){
      const float f0  = sigm(r_f + x_f0 + wb_f);
      const float iw0 = sigm(r_i + x_i0 + wb_i);
      const float g0  = tanhf(r_g + x_g0 + wb_g);
      const float cw0 = f0 * c1 + iw0 * g0;
      const float f1  = sigm(r_f + x_f1 + wb_f);
      const float iw1 = sigm(r_i + x_i1 + wb_i);
      const float g1  = tanhf(r_g + x_g1 + wb_g);
      const float cw1 = f1 * c1 + iw1 * g1;
      // gen = production step + 1; consumers poll p0>=t_c, p1>=t_c-2
      pub64(pnd + ((size_t)((t + 1) & 3) * 2 + 0) * Hq + J, cw0, (unsigned)(t + 1));
      pub64(pnd + ((size_t)((t + 3) & 3) * 2 + 1) * Hq + J, cw1, (unsigned)(t + 1));
    }
    // no barrier: next A1 touches only shH[par^1]/shx[par^1] (disjoint);
    // sh_p0/sh_p1 rewrites are fenced by next S1; shxw[par] reads done pre-S2.
  }
}

extern "C" void kernel_launch(void* const* d_in, const int* in_sizes, int n_in,
                              void* d_out, int out_size, void* d_ws, size_t ws_size,
                              hipStream_t stream){
  const float* char_emb = (const float*)d_in[0];
  const int*   word_ids = (const int*)d_in[1];
  const float* sense    = (const float*)d_in[2];
  const float* w_ih     = (const float*)d_in[3];
  const float* w_hh     = (const float*)d_in[4];
  const float* bb       = (const float*)d_in[5];
  const float* aw_ih    = (const float*)d_in[6];
  const float* aw_hh    = (const float*)d_in[7];
  const float* ab       = (const float*)d_in[8];
  const float* ww_ih    = (const float*)d_in[9];
  const float* ww_hh    = (const float*)d_in[10];
  const float* wb       = (const float*)d_in[11];
  unsigned char* ws = (unsigned char*)d_ws;
  float* out = (float*)d_out;

  // zero all generation words (h_pub + pend) — ws is re-poisoned before every launch
  hipMemsetAsync(ws, 0, WIHT_OFF, stream);

  // one-time (per launch) weight convert+transpose to bf16
  transpose_bf16<<<512, 256, 0, stream>>>(w_ih,  (__hip_bfloat16*)(ws + WIHT_OFF),  7, 128*1536, 1536);
  transpose_bf16<<<512, 256, 0, stream>>>(w_hh,  (__hip_bfloat16*)(ws + WHHT_OFF),  9, 512*1536, 1536);
  transpose_bf16<<<512, 256, 0, stream>>>(aw_ih, (__hip_bfloat16*)(ws + AWIHT_OFF), 7, 128*512,  512);
  transpose_bf16<<<512, 256, 0, stream>>>(aw_hh, (__hip_bfloat16*)(ws + AWHHT_OFF), 9, 512*512,  512);
  transpose_bf16<<<512, 256, 0, stream>>>(ww_ih, (__hip_bfloat16*)(ws + WWIHT_OFF), 7, 128*1536, 1536);
  transpose_bf16<<<512, 256, 0, stream>>>(ww_hh, (__hip_bfloat16*)(ws + WWHHT_OFF), 9, 512*1536, 1536);

  dim3 grid(Bq, NWG);   // x = seq (XCD-local heuristic), y = wg slice; 128 WGs
  lattice_main<<<grid, NTHR, 0, stream>>>(char_emb, word_ids, sense, bb, ab, wb, ws, out);
}

// Round 10
// 5949.697 us; speedup vs baseline: 1.9679x; 1.9679x over previous
//
#include <hip/hip_runtime.h>
#include <hip/hip_bf16.h>

// LatticeLSTM on MI355X — Round 10: R8 base + barrier-drain elimination.
//  - REVERT R9's 512-thr config (it capped VGPR at 128 -> spilled the weight
//    registers -> 2x regression). 256 thr, launch_bounds(256,1), VGPR-rich.
//  - x/char + sense staging now loads straight into REGISTERS (each thread
//    loads exactly the 8 floats per array it consumes), issued at the TOP of
//    the step interval for t+1 -> a full interval old at any barrier, so
//    __syncthreads() vmcnt drains no longer absorb a fresh MALL round trip.
//    (S2 previously drained ~0.3us-old sense-row loads every step.)
//  - out_h/out_c stores moved to just AFTER S2 -> drain at S1(t+1) (~1us old).
//  - Speculative h-load issued right after h publish (before B-pre) -> B2's
//    first check rides an already-in-flight load.
//  - Protocol unchanged from R8: u64 {val,gen} relaxed agent-scope atomics;
//    packed bf16 h broadcast (2 cols/word, 256 words); fp32 pend per column.
// pmask is data-independent: m0=(t>=1), m1=(t>=3); c_plain only at t=0.
// Progress needs all 256 WGs co-resident (1 WG/CU; LDS 8KB, VGPR<512 @ (256,1)).

#define Bq 8
#define Tq 1024
#define DCq 128
#define Hq 512
#define NWG 32
#define NTHR 256

typedef unsigned long long u64;

// ws byte offsets
#define HPUB_OFF  0u         // u64 h_pub[8][2][256]     = 32768 (gap to 65536)
#define PENDP_OFF 65536u     // u64 pend[8][4][2][512]   = 262144
#define WIHT_OFF  327680u    // bf16 [1536][128]
#define WHHT_OFF  720896u    // bf16 [1536][512]
#define AWIHT_OFF 2293760u   // bf16 [512][128]
#define AWHHT_OFF 2424832u   // bf16 [512][512]
#define WWIHT_OFF 2949120u   // bf16 [1536][128]
#define WWHHT_OFF 3342336u   // bf16 [1536][512]  (end 4915200)

__device__ __forceinline__ float bflo(unsigned u){ return __uint_as_float(u << 16); }
__device__ __forceinline__ float bfhi(unsigned u){ return __uint_as_float(u & 0xffff0000u); }
__device__ __forceinline__ float sigm(float x){ return 1.0f / (1.0f + __expf(-x)); }

// fp32 -> bf16 bits (RNE)
__device__ __forceinline__ unsigned f2bf(float f){
  unsigned u = __float_as_uint(f);
  u += 0x7fffu + ((u >> 16) & 1u);
  return u >> 16;
}

__device__ __forceinline__ void fma4(float& acc, uint2 w, float4 v){
  acc = fmaf(bflo(w.x), v.x, acc);
  acc = fmaf(bfhi(w.x), v.y, acc);
  acc = fmaf(bflo(w.y), v.z, acc);
  acc = fmaf(bfhi(w.y), v.w, acc);
}

__device__ __forceinline__ float red16(float x){
  x += __shfl_xor(x, 8, 16);
  x += __shfl_xor(x, 4, 16);
  x += __shfl_xor(x, 2, 16);
  x += __shfl_xor(x, 1, 16);
  return x;
}

__device__ __forceinline__ u64 pack64(float v, unsigned gen){
  return ((u64)gen << 32) | (u64)__float_as_uint(v);
}
__device__ __forceinline__ void st64(u64* p, u64 w){
  __hip_atomic_store(p, w, __ATOMIC_RELAXED, __HIP_MEMORY_SCOPE_AGENT);
}
__device__ __forceinline__ void pub64(u64* p, float v, unsigned gen){
  st64(p, pack64(v, gen));
}
__device__ __forceinline__ u64 ld64(const u64* p){
  return __hip_atomic_load(p, __ATOMIC_RELAXED, __HIP_MEMORY_SCOPE_AGENT);
}
__device__ __forceinline__ unsigned genof(u64 v){ return (unsigned)(v >> 32); }
__device__ __forceinline__ float valof(u64 v){ return __uint_as_float((unsigned)v); }

// src [K][N] fp32 -> dst [N][K] bf16 (transpose + convert). K is pow2.
__global__ void transpose_bf16(const float* __restrict__ src, __hip_bfloat16* __restrict__ dst,
                               int kshift, int total, int N){
  const int K = 1 << kshift;
  for (int idx = blockIdx.x * blockDim.x + threadIdx.x; idx < total;
       idx += gridDim.x * blockDim.x){
    int n = idx >> kshift;
    int k = idx & (K - 1);
    dst[idx] = __float2bfloat16(src[(size_t)k * N + n]);
  }
}

__global__ void __launch_bounds__(NTHR, 1)
lattice_main(const float* __restrict__ char_emb,
             const int*   __restrict__ word_ids,
             const float* __restrict__ sense_table,
             const float* __restrict__ bias_b,
             const float* __restrict__ bias_ab,
             const float* __restrict__ bias_wb,
             unsigned char* __restrict__ ws,
             float* __restrict__ out)
{
  const int seq  = blockIdx.x;
  const int wg   = blockIdx.y;
  const int tid  = threadIdx.x;
  const int grp  = tid >> 4;
  const int lane = tid & 15;
  const int J    = wg * 16 + grp;               // owned H column
  const int i0   = tid * 2, i1 = tid * 2 + 1;   // pend poll columns

  u64* hpub = (u64*)(ws + HPUB_OFF)  + (size_t)seq * 2 * 256;     // [parity][word]
  u64* pnd  = (u64*)(ws + PENDP_OFF) + (size_t)seq * 4 * 2 * Hq;  // [slot][k][col]

  const uint2* w_ihT  = (const uint2*)(ws + WIHT_OFF);
  const uint2* w_hhT  = (const uint2*)(ws + WHHT_OFF);
  const uint2* aw_ihT = (const uint2*)(ws + AWIHT_OFF);
  const uint2* aw_hhT = (const uint2*)(ws + AWHHT_OFF);
  const uint2* ww_ihT = (const uint2*)(ws + WWIHT_OFF);
  const uint2* ww_hhT = (const uint2*)(ws + WWHHT_OFF);

  // ---- hoist ALL weights into registers (addresses are t-invariant) ----
  uint2 Rwhh_i[8], Rwhh_o[8], Rwhh_g[8], Rawhh[8];
  uint2 Rwwh_f[8], Rwwh_i[8], Rwwh_g[8];
  uint2 Rwih_i[2], Rwih_o[2], Rwih_g[2], Rawih[2];
  uint2 Rwwi_f[2], Rwwi_i[2], Rwwi_g[2];
  {
    const uint2* whh_i = w_hhT  + (size_t)(0*Hq + J) * 128;
    const uint2* whh_o = w_hhT  + (size_t)(1*Hq + J) * 128;
    const uint2* whh_g = w_hhT  + (size_t)(2*Hq + J) * 128;
    const uint2* awhh  = aw_hhT + (size_t)J * 128;
    const uint2* wwh_f = ww_hhT + (size_t)(0*Hq + J) * 128;
    const uint2* wwh_i = ww_hhT + (size_t)(1*Hq + J) * 128;
    const uint2* wwh_g = ww_hhT + (size_t)(2*Hq + J) * 128;
#pragma unroll
    for (int it = 0; it < 8; ++it){
      const int q = it * 16 + lane;
      Rwhh_i[it] = whh_i[q];  Rwhh_o[it] = whh_o[q];  Rwhh_g[it] = whh_g[q];
      Rawhh[it]  = awhh[q];
      Rwwh_f[it] = wwh_f[q];  Rwwh_i[it] = wwh_i[q];  Rwwh_g[it] = wwh_g[q];
    }
    const uint2* wih_i = w_ihT  + (size_t)(0*Hq + J) * 32;
    const uint2* wih_o = w_ihT  + (size_t)(1*Hq + J) * 32;
    const uint2* wih_g = w_ihT  + (size_t)(2*Hq + J) * 32;
    const uint2* awih  = aw_ihT + (size_t)J * 32;
    const uint2* wwi_f = ww_ihT + (size_t)(0*Hq + J) * 32;
    const uint2* wwi_i = ww_ihT + (size_t)(1*Hq + J) * 32;
    const uint2* wwi_g = ww_ihT + (size_t)(2*Hq + J) * 32;
#pragma unroll
    for (int it = 0; it < 2; ++it){
      const int q = it * 16 + lane;
      Rwih_i[it] = wih_i[q];  Rwih_o[it] = wih_o[q];  Rwih_g[it] = wih_g[q];
      Rawih[it]  = awih[q];
      Rwwi_f[it] = wwi_f[q];  Rwwi_i[it] = wwi_i[q];  Rwwi_g[it] = wwi_g[q];
    }
  }

  const float b_i  = bias_b[J], b_o = bias_b[Hq + J], b_g = bias_b[2*Hq + J];
  const float ab_J = bias_ab[J];
  const float wb_f = bias_wb[J], wb_i = bias_wb[Hq + J], wb_g = bias_wb[2*Hq + J];

  float* out_h = out + (size_t)seq * Tq * Hq;            // hs block
  float* out_c = out + ((size_t)Bq + seq) * Tq * Hq;     // cs block

  __shared__ __align__(16) float shH[2][Hq];      // h by parity: shH[t&1] = h(t)
  __shared__ __align__(16) float sh_p0[Hq];
  __shared__ __align__(16) float sh_p1[Hq];

  // per-thread x/sense element offsets (same every step)
  const int ka = lane * 4;            // it=0 chunk
  const int kb = 64 + lane * 4;       // it=1 chunk
  const float* cbase = char_emb + (size_t)seq * Tq * DCq;
  const int*   wbase = word_ids + (size_t)seq * Tq * 2;

  // ---- pre-loop: zeros + register staging for t=0 ----
  shH[0][i0] = 0.f; shH[0][i1] = 0.f;
  shH[1][i0] = 0.f; shH[1][i1] = 0.f;
  sh_p0[i0] = 0.f; sh_p0[i1] = 0.f;
  sh_p1[i0] = 0.f; sh_p1[i1] = 0.f;
  float4 xc0, xc1, xw0c0, xw0c1, xw1c0, xw1c1;
  {
    const int w0 = wbase[0], w1 = wbase[1];
    xc0   = *(const float4*)(cbase + ka);
    xc1   = *(const float4*)(cbase + kb);
    xw0c0 = *(const float4*)(sense_table + (size_t)w0 * DCq + ka);
    xw0c1 = *(const float4*)(sense_table + (size_t)w0 * DCq + kb);
    xw1c0 = *(const float4*)(sense_table + (size_t)w1 * DCq + ka);
    xw1c1 = *(const float4*)(sense_table + (size_t)w1 * DCq + kb);
  }
  __syncthreads();

  float h1 = 0.f, c1 = 0.f;

  for (int t = 0; t < Tq; ++t){
    const int par = t & 1;
    const float* hprev = shH[par ^ 1];     // h(t-1)

    // ---- TOP: prefetch x/sense for t+1 into registers (a full interval
    //      before any barrier that could drain them) ----
    const int tn = (t + 1 < Tq) ? t + 1 : t;
    const int w0n = wbase[2 * tn], w1n = wbase[2 * tn + 1];
    float4 xn0   = *(const float4*)(cbase + (size_t)tn * DCq + ka);
    float4 xn1   = *(const float4*)(cbase + (size_t)tn * DCq + kb);
    float4 xw0n0 = *(const float4*)(sense_table + (size_t)w0n * DCq + ka);
    float4 xw0n1 = *(const float4*)(sense_table + (size_t)w0n * DCq + kb);
    float4 xw1n0 = *(const float4*)(sense_table + (size_t)w1n * DCq + ka);
    float4 xw1n1 = *(const float4*)(sense_table + (size_t)w1n * DCq + kb);

    // ---- pend PREFETCH (latency hides under A1) ----
    const u64* p0 = pnd + ((size_t)(t & 3) * 2 + 0) * Hq;
    const u64* p1 = pnd + ((size_t)(t & 3) * 2 + 1) * Hq;
    u64 qa = 0, qb = 0, qc = 0, qd = 0;
    if (t >= 1){ qa = ld64(p0 + i0); qb = ld64(p0 + i1); }
    if (t >= 3){ qc = ld64(p1 + i0); qd = ld64(p1 + i1); }

    // ---- A1: i/o/g/xa matvecs ----
    float a_i = 0.f, a_o = 0.f, a_g = 0.f, a_xa = 0.f;
#pragma unroll
    for (int it = 0; it < 8; ++it){
      const int k0 = it * 64 + lane * 4;
      float4 hv = *(const float4*)(hprev + k0);
      fma4(a_i, Rwhh_i[it], hv);
      fma4(a_o, Rwhh_o[it], hv);
      fma4(a_g, Rwhh_g[it], hv);
    }
    fma4(a_i,  Rwih_i[0], xc0);  fma4(a_i,  Rwih_i[1], xc1);
    fma4(a_o,  Rwih_o[0], xc0);  fma4(a_o,  Rwih_o[1], xc1);
    fma4(a_g,  Rwih_g[0], xc0);  fma4(a_g,  Rwih_g[1], xc1);
    fma4(a_xa, Rawih[0],  xc0);  fma4(a_xa, Rawih[1],  xc1);
    a_i  = red16(a_i);  a_o  = red16(a_o);  a_g  = red16(a_g);  a_xa = red16(a_xa);

    // ---- A2: check prefetched pend; re-poll on miss ----
    if (t >= 3){
      const unsigned tg0 = (unsigned)t, tg1 = (unsigned)(t - 2);
      while (!(genof(qa) >= tg0 && genof(qb) >= tg0 &&
               genof(qc) >= tg1 && genof(qd) >= tg1)){
        qa = ld64(p0 + i0); qb = ld64(p0 + i1);
        qc = ld64(p1 + i0); qd = ld64(p1 + i1);
      }
      sh_p0[i0] = valof(qa); sh_p0[i1] = valof(qb);
      sh_p1[i0] = valof(qc); sh_p1[i1] = valof(qd);
    } else if (t >= 1){
      const unsigned tg0 = (unsigned)t;
      while (!(genof(qa) >= tg0 && genof(qb) >= tg0)){
        qa = ld64(p0 + i0); qb = ld64(p0 + i1);
      }
      sh_p0[i0] = valof(qa); sh_p0[i1] = valof(qb);
      // sh_p1 stays zero (m1=0 for t<3)
    }
    __syncthreads();   // S1 — drains: prefetch regs (old), out stores (old)

    // ---- A3: alpha matvecs + gates -> publish h ----
    float a_p0 = 0.f, a_p1 = 0.f;
#pragma unroll
    for (int it = 0; it < 8; ++it){
      const int k0 = it * 64 + lane * 4;
      float4 p0v = *(const float4*)(sh_p0 + k0);
      float4 p1v = *(const float4*)(sh_p1 + k0);
      fma4(a_p0, Rawhh[it], p0v);
      fma4(a_p1, Rawhh[it], p1v);
    }
    a_p0 = red16(a_p0); a_p1 = red16(a_p1);

    const float gi = sigm(a_i + b_i);
    const float go = sigm(a_o + b_o);
    const float gg = tanhf(a_g + b_g);
    if (t == 0){
      c1 = gi * gg;                       // c_plain with c=0
    } else {
      const float base = a_xa + ab_J;
      const float ea0 = __expf(sigm(base + a_p0));   // m0=1 for t>=1
      const float ei  = __expf(gi);
      float num = ei * gg + ea0 * sh_p0[J];
      float den = ei + ea0;
      if (t >= 3){                                    // m1=1 for t>=3
        const float ea1 = __expf(sigm(base + a_p1));
        num += ea1 * sh_p1[J];
        den += ea1;
      }
      c1 = num / den;
    }
    h1 = go * tanhf(c1);
    // pair h1 of adjacent groups: lane l <-> l^16 (groups 2k <-> 2k+1)
    const float h1o = __shfl_xor(h1, 16);
    if (lane == 0 && (grp & 1) == 0){
      const u64 w = ((u64)(unsigned)(t + 1) << 32)
                  | ((u64)f2bf(h1o) << 16) | (u64)f2bf(h1);
      st64(hpub + (size_t)par * 256 + (J >> 1), w);   // publish h FIRST
    }
    // speculative h-load: in flight across B-pre
    const u64* hp = hpub + (size_t)par * 256 + tid;
    u64 ha = ld64(hp);

    // ---- B-pre (h NOT needed): x-word matvecs from registers ----
    float x_f0 = 0.f, x_i0 = 0.f, x_g0 = 0.f, x_f1 = 0.f, x_i1 = 0.f, x_g1 = 0.f;
    fma4(x_f0, Rwwi_f[0], xw0c0);  fma4(x_f0, Rwwi_f[1], xw0c1);
    fma4(x_i0, Rwwi_i[0], xw0c0);  fma4(x_i0, Rwwi_i[1], xw0c1);
    fma4(x_g0, Rwwi_g[0], xw0c0);  fma4(x_g0, Rwwi_g[1], xw0c1);
    fma4(x_f1, Rwwi_f[0], xw1c0);  fma4(x_f1, Rwwi_f[1], xw1c1);
    fma4(x_i1, Rwwi_i[0], xw1c0);  fma4(x_i1, Rwwi_i[1], xw1c1);
    fma4(x_g1, Rwwi_g[0], xw1c0);  fma4(x_g1, Rwwi_g[1], xw1c1);
    x_f0 = red16(x_f0); x_i0 = red16(x_i0); x_g0 = red16(x_g0);
    x_f1 = red16(x_f1); x_i1 = red16(x_i1); x_g1 = red16(x_g1);

    // ---- B2: poll packed h(t) (spec load first) ----
    {
      const unsigned tg = (unsigned)(t + 1);
      u64 b = ld64(hp);
      for (;;){
        if (genof(ha) >= tg) break;
        ha = ld64(hp);
        if (genof(b) >= tg){ ha = b; break; }
        b = ld64(hp);
      }
      shH[par][i0] = bflo((unsigned)ha & 0xffffu);
      shH[par][i1] = bflo(((unsigned)ha >> 16) & 0xffffu);
    }
    __syncthreads();   // S2 — drains: h publish (needed), polls (cheap)

    // ---- out stores AFTER S2: drain at S1(t+1), off the critical wait ----
    if (lane == 0){
      out_h[(size_t)t * Hq + J] = h1;
      out_c[(size_t)t * Hq + J] = c1;
    }

    // ---- B3: word h-matvecs + gates -> publish pend ----
    float r_f = 0.f, r_i = 0.f, r_g = 0.f;
#pragma unroll
    for (int it = 0; it < 8; ++it){
      const int k0 = it * 64 + lane * 4;
      float4 hv = *(const float4*)(shH[par] + k0);
      fma4(r_f, Rwwh_f[it], hv);
      fma4(r_i, Rwwh_i[it], hv);
      fma4(r_g, Rwwh_g[it], hv);
    }
    r_f = red16(r_f); r_i = red16(r_i); r_g = red16(r_g);

    if (lane == 0){
      const float f0  = sigm(r_f + x_f0 + wb_f);
      const float iw0 = sigm(r_i + x_i0 + wb_i);
      const float g0  = tanhf(r_g + x_g0 + wb_g);
      const float cw0 = f0 * c1 + iw0 * g0;
      const float f1  = sigm(r_f + x_f1 + wb_f);
      const float iw1 = sigm(r_i + x_i1 + wb_i);
      const float g1  = tanhf(r_g + x_g1 + wb_g);
      const float cw1 = f1 * c1 + iw1 * g1;
      // gen = production step + 1; consumers poll p0>=t_c, p1>=t_c-2
      pub64(pnd + ((size_t)((t + 1) & 3) * 2 + 0) * Hq + J, cw0, (unsigned)(t + 1));
      pub64(pnd + ((size_t)((t + 3) & 3) * 2 + 1) * Hq + J, cw1, (unsigned)(t + 1));
    }

    // rotate register staging: next -> current
    xc0 = xn0; xc1 = xn1;
    xw0c0 = xw0n0; xw0c1 = xw0n1;
    xw1c0 = xw1n0; xw1c1 = xw1n1;
    // no extra barrier: next A1 reads shH[par^1] (last written pre-S2(t-1)),
    // sh_p0/p1 rewrites (A2 of t+1) are separated from A3(t) reads by S2(t).
  }
}

extern "C" void kernel_launch(void* const* d_in, const int* in_sizes, int n_in,
                              void* d_out, int out_size, void* d_ws, size_t ws_size,
                              hipStream_t stream){
  const float* char_emb = (const float*)d_in[0];
  const int*   word_ids = (const int*)d_in[1];
  const float* sense    = (const float*)d_in[2];
  const float* w_ih     = (const float*)d_in[3];
  const float* w_hh     = (const float*)d_in[4];
  const float* bb       = (const float*)d_in[5];
  const float* aw_ih    = (const float*)d_in[6];
  const float* aw_hh    = (const float*)d_in[7];
  const float* ab       = (const float*)d_in[8];
  const float* ww_ih    = (const float*)d_in[9];
  const float* ww_hh    = (const float*)d_in[10];
  const float* wb       = (const float*)d_in[11];
  unsigned char* ws = (unsigned char*)d_ws;
  float* out = (float*)d_out;

  // zero all generation words (h_pub + pend) — ws is re-poisoned before every launch
  hipMemsetAsync(ws, 0, WIHT_OFF, stream);

  // one-time (per launch) weight convert+transpose to bf16
  transpose_bf16<<<512, 256, 0, stream>>>(w_ih,  (__hip_bfloat16*)(ws + WIHT_OFF),  7, 128*1536, 1536);
  transpose_bf16<<<512, 256, 0, stream>>>(w_hh,  (__hip_bfloat16*)(ws + WHHT_OFF),  9, 512*1536, 1536);
  transpose_bf16<<<512, 256, 0, stream>>>(aw_ih, (__hip_bfloat16*)(ws + AWIHT_OFF), 7, 128*512,  512);
  transpose_bf16<<<512, 256, 0, stream>>>(aw_hh, (__hip_bfloat16*)(ws + AWHHT_OFF), 9, 512*512,  512);
  transpose_bf16<<<512, 256, 0, stream>>>(ww_ih, (__hip_bfloat16*)(ws + WWIHT_OFF), 7, 128*1536, 1536);
  transpose_bf16<<<512, 256, 0, stream>>>(ww_hh, (__hip_bfloat16*)(ws + WWHHT_OFF), 9, 512*1536, 1536);

  dim3 grid(Bq, NWG);   // x = seq (XCD-local heuristic), y = wg slice; 256 WGs
  lattice_main<<<grid, NTHR, 0, stream>>>(char_emb, word_ids, sense, bb, ab, wb, ws, out);
}